// Round 1
// baseline (304.687 us; speedup 1.0000x reference)
//
#include <hip/hip_runtime.h>
#include <hip/hip_bf16.h>
#include <stdint.h>

// ---------------------------------------------------------------------------
// OptimizedMultiHeadAttn: x:[2,2048,1024] f32, attn_w:[3072,1024], attn_b:[3072],
// proj_w:[1024,1024], proj_b:[1024]  ->  out:[2,2048,1024] f32
// Pipeline: cvt(x,attn_w,proj_w -> bf16) -> QKV gemm_bt (scatter to Q/K/V^T)
//           -> flash attention (causal) -> proj gemm_bt (f32 out + bias)
// ---------------------------------------------------------------------------

typedef __bf16 bf16_t;
typedef __bf16 bf16x8 __attribute__((ext_vector_type(8)));
typedef float f32x4 __attribute__((ext_vector_type(4)));

#define B_SZ 2
#define S_LEN 2048
#define D_MODEL 1024
#define N_HEADS 16
#define D_HEAD 64
#define M_ROWS (B_SZ * S_LEN)          // 4096
#define QKV_N (3 * N_HEADS * D_HEAD)   // 3072

// workspace layout (bytes); total 48 MiB
#define OFF_XB  (0ull)          // x bf16      [4096,1024]  8 MiB
#define OFF_WB  (8ull  << 20)   // attn_w bf16 [3072,1024]  6 MiB
#define OFF_PWB (14ull << 20)   // proj_w bf16 [1024,1024]  2 MiB
#define OFF_Q   (16ull << 20)   // Q bf16 [B,H,S,DK], pre-scaled by 0.125
#define OFF_K   (24ull << 20)   // K bf16 [B,H,S,DK]
#define OFF_VT  (32ull << 20)   // V^T bf16 [B,H,DK,S]
#define OFF_AO  (40ull << 20)   // attn out bf16 [4096,1024]

__device__ __forceinline__ unsigned short f2bf_u(float f) {
  union { float f; unsigned u; } v; v.f = f;
  unsigned r = v.u + 0x7fffu + ((v.u >> 16) & 1u);  // RNE
  return (unsigned short)(r >> 16);
}
__device__ __forceinline__ bf16_t f2bf(float f) {
  unsigned short u = f2bf_u(f);
  return __builtin_bit_cast(bf16_t, u);
}

// ---------------------------------------------------------------------------
__global__ void cvt_f32_bf16(const float* __restrict__ src,
                             bf16_t* __restrict__ dst, int n4) {
  int i = blockIdx.x * blockDim.x + threadIdx.x;
  if (i >= n4) return;
  float4 f = reinterpret_cast<const float4*>(src)[i];
  ushort4 o;
  o.x = f2bf_u(f.x); o.y = f2bf_u(f.y); o.z = f2bf_u(f.z); o.w = f2bf_u(f.w);
  reinterpret_cast<ushort4*>(dst)[i] = o;
}

// ---------------------------------------------------------------------------
// gemm_bt: C[M,N] = A[M,K] * Bt[N,K]^T + bias, 128x128 tile, BK=64, 4 waves.
// global_load_lds(16B) staging; XOR-swizzled source so LDS reads are
// (nearly) conflict-free (rule #21: linear dest + inverse-swz source + swz read).
#define BM 128
#define BN 128
#define BK 64

__device__ __forceinline__ void gload_lds16(const bf16_t* g, bf16_t* l) {
  __builtin_amdgcn_global_load_lds((__attribute__((address_space(1))) void*)g,
                                   (__attribute__((address_space(3))) void*)l,
                                   16, 0, 0);
}

__device__ __forceinline__ bf16x8 lds_frag(const bf16_t* lds, int row, int kchunk) {
  int pos = kchunk ^ (row & 7);
  return *reinterpret_cast<const bf16x8*>(lds + row * BK + pos * 8);
}

// EPI 0: QKV epilogue (scatter bf16 Q/K/V^T, Q pre-scaled 0.125)
// EPI 1: proj epilogue (f32 out + bias)
template <int EPI>
__global__ __launch_bounds__(256, 2) void gemm_bt(
    const bf16_t* __restrict__ A, const bf16_t* __restrict__ Bt,
    const float* __restrict__ bias,
    float* __restrict__ fout,
    bf16_t* __restrict__ qout, bf16_t* __restrict__ kout,
    bf16_t* __restrict__ vtout,
    int M, int N, int K) {
  __shared__ bf16_t As[BM * BK];
  __shared__ bf16_t Bs[BN * BK];
  const int tid = threadIdx.x;
  const int lane = tid & 63;
  const int wid = tid >> 6;
  const int wr = wid >> 1, wc = wid & 1;
  const int cl = lane & 15, hl = lane >> 4;
  const int m0 = blockIdx.y * BM, n0 = blockIdx.x * BN;

  f32x4 acc[4][4];
  #pragma unroll
  for (int m = 0; m < 4; ++m)
    #pragma unroll
    for (int n = 0; n < 4; ++n)
      acc[m][n] = (f32x4){0.f, 0.f, 0.f, 0.f};

  for (int kt = 0; kt < K; kt += BK) {
    #pragma unroll
    for (int it = 0; it < 4; ++it) {
      int chunk = it * 256 + tid;
      int row = chunk >> 3, cpos = chunk & 7;
      int csrc = cpos ^ (row & 7);                     // inverse-swizzled source
      bf16_t* ldsA = As + (it * 256 + wid * 64) * 8;   // wave-uniform dest base
      bf16_t* ldsB = Bs + (it * 256 + wid * 64) * 8;
      gload_lds16(A  + (size_t)(m0 + row) * K + kt + csrc * 8, ldsA);
      gload_lds16(Bt + (size_t)(n0 + row) * K + kt + csrc * 8, ldsB);
    }
    __syncthreads();

    bf16x8 af[2][4], bfr[2][4];
    #pragma unroll
    for (int kk = 0; kk < 2; ++kk) {
      #pragma unroll
      for (int m = 0; m < 4; ++m)
        af[kk][m] = lds_frag(As, wr * 64 + m * 16 + cl, kk * 4 + hl);
      #pragma unroll
      for (int n = 0; n < 4; ++n)
        bfr[kk][n] = lds_frag(Bs, wc * 64 + n * 16 + cl, kk * 4 + hl);
    }
    #pragma unroll
    for (int m = 0; m < 4; ++m)
      #pragma unroll
      for (int n = 0; n < 4; ++n) {
        acc[m][n] = __builtin_amdgcn_mfma_f32_16x16x32_bf16(af[0][m], bfr[0][n], acc[m][n], 0, 0, 0);
        acc[m][n] = __builtin_amdgcn_mfma_f32_16x16x32_bf16(af[1][m], bfr[1][n], acc[m][n], 0, 0, 0);
      }
    __syncthreads();
  }

  // epilogue: C/D layout col=lane&15, row=(lane>>4)*4+j (m89-verified)
  #pragma unroll
  for (int n = 0; n < 4; ++n) {
    int ng = n0 + wc * 64 + n * 16 + cl;
    float bv = bias[ng];
    if constexpr (EPI == 0) {
      int part = ng >> 10;         // 0=Q 1=K 2=V
      int r = ng & 1023;
      int h = r >> 6, dk = r & 63;
      #pragma unroll
      for (int m = 0; m < 4; ++m)
        #pragma unroll
        for (int j = 0; j < 4; ++j) {
          int mg = m0 + wr * 64 + m * 16 + hl * 4 + j;
          int b = mg >> 11, s = mg & 2047;
          float val = acc[m][n][j] + bv;
          size_t bh = (size_t)(b * N_HEADS + h);
          if (part == 0)
            qout[(bh * S_LEN + s) * D_HEAD + dk] = f2bf(val * 0.125f);
          else if (part == 1)
            kout[(bh * S_LEN + s) * D_HEAD + dk] = f2bf(val);
          else
            vtout[(bh * D_HEAD + dk) * S_LEN + s] = f2bf(val);
        }
    } else {
      #pragma unroll
      for (int m = 0; m < 4; ++m)
        #pragma unroll
        for (int j = 0; j < 4; ++j) {
          int mg = m0 + wr * 64 + m * 16 + hl * 4 + j;
          fout[(size_t)mg * N + ng] = acc[m][n][j] + bv;
        }
    }
  }
}

// ---------------------------------------------------------------------------
// Flash attention, causal. Grid (S/64, B*H). 4 waves/block, 16 Q-rows/wave,
// KBLK=64. K/V read directly from global (L3-resident). Online softmax in f32.
__global__ __launch_bounds__(256, 2) void attn_fwd(
    const bf16_t* __restrict__ q,    // [B,H,S,DK], pre-scaled by 0.125
    const bf16_t* __restrict__ k,    // [B,H,S,DK]
    const bf16_t* __restrict__ vt,   // [B,H,DK,S]
    bf16_t* __restrict__ ao) {       // [B*S, H*DK]
  const int qt = blockIdx.x;
  const int bh = blockIdx.y;
  const int tid = threadIdx.x;
  const int lane = tid & 63, w = tid >> 6;
  const int cl = lane & 15, hl = lane >> 4;
  const bf16_t* qb = q + (size_t)bh * S_LEN * D_HEAD;
  const bf16_t* kb = k + (size_t)bh * S_LEN * D_HEAD;
  const bf16_t* vb = vt + (size_t)bh * D_HEAD * S_LEN;
  const int qrow0 = qt * 64 + w * 16;

  __shared__ bf16_t plds[4][16][72];   // per-wave P tile, padded stride

  // Q fragments (A-operand): row=lane&15, k=(lane>>4)*8 (+kk*32)
  bf16x8 qf0 = *reinterpret_cast<const bf16x8*>(qb + (size_t)(qrow0 + cl) * D_HEAD + hl * 8);
  bf16x8 qf1 = *reinterpret_cast<const bf16x8*>(qb + (size_t)(qrow0 + cl) * D_HEAD + 32 + hl * 8);

  float mrow[4], lrow[4];
  f32x4 acco[4];
  #pragma unroll
  for (int j = 0; j < 4; ++j) { mrow[j] = -1e30f; lrow[j] = 0.f; }
  #pragma unroll
  for (int db = 0; db < 4; ++db) acco[db] = (f32x4){0.f, 0.f, 0.f, 0.f};

  for (int kt = 0; kt <= qt; ++kt) {
    f32x4 sacc[4];
    #pragma unroll
    for (int nb = 0; nb < 4; ++nb) sacc[nb] = (f32x4){0.f, 0.f, 0.f, 0.f};

    #pragma unroll
    for (int nb = 0; nb < 4; ++nb) {
      const bf16_t* kr = kb + (size_t)(kt * 64 + nb * 16 + cl) * D_HEAD + hl * 8;
      bf16x8 kf0 = *reinterpret_cast<const bf16x8*>(kr);
      bf16x8 kf1 = *reinterpret_cast<const bf16x8*>(kr + 32);
      sacc[nb] = __builtin_amdgcn_mfma_f32_16x16x32_bf16(qf0, kf0, sacc[nb], 0, 0, 0);
      sacc[nb] = __builtin_amdgcn_mfma_f32_16x16x32_bf16(qf1, kf1, sacc[nb], 0, 0, 0);
    }

    if (kt == qt) {  // diagonal tile: causal mask
      #pragma unroll
      for (int nb = 0; nb < 4; ++nb)
        #pragma unroll
        for (int j = 0; j < 4; ++j) {
          int colg = kt * 64 + nb * 16 + cl;
          int rowg = qrow0 + hl * 4 + j;
          if (colg > rowg) sacc[nb][j] = -1e30f;
        }
    }

    // online softmax (rows live on 16-lane groups; reduce over lane&15)
    #pragma unroll
    for (int j = 0; j < 4; ++j) {
      float tmax = fmaxf(fmaxf(sacc[0][j], sacc[1][j]), fmaxf(sacc[2][j], sacc[3][j]));
      tmax = fmaxf(tmax, __shfl_xor(tmax, 1));
      tmax = fmaxf(tmax, __shfl_xor(tmax, 2));
      tmax = fmaxf(tmax, __shfl_xor(tmax, 4));
      tmax = fmaxf(tmax, __shfl_xor(tmax, 8));
      float mnew = fmaxf(mrow[j], tmax);
      float corr = __expf(mrow[j] - mnew);
      mrow[j] = mnew;
      float rsum = 0.f;
      #pragma unroll
      for (int nb = 0; nb < 4; ++nb) {
        float p = __expf(sacc[nb][j] - mnew);
        sacc[nb][j] = p;
        rsum += p;
      }
      rsum += __shfl_xor(rsum, 1);
      rsum += __shfl_xor(rsum, 2);
      rsum += __shfl_xor(rsum, 4);
      rsum += __shfl_xor(rsum, 8);
      lrow[j] = lrow[j] * corr + rsum;
      #pragma unroll
      for (int db = 0; db < 4; ++db) acco[db][j] *= corr;
    }

    // P -> bf16 via wave-private LDS (C-layout -> A-layout transpose)
    #pragma unroll
    for (int nb = 0; nb < 4; ++nb)
      #pragma unroll
      for (int j = 0; j < 4; ++j)
        plds[w][hl * 4 + j][nb * 16 + cl] = f2bf(sacc[nb][j]);

    bf16x8 pf0 = *reinterpret_cast<const bf16x8*>(&plds[w][cl][hl * 8]);
    bf16x8 pf1 = *reinterpret_cast<const bf16x8*>(&plds[w][cl][32 + hl * 8]);

    #pragma unroll
    for (int db = 0; db < 4; ++db) {
      const bf16_t* vr = vb + (size_t)(db * 16 + cl) * S_LEN + kt * 64 + hl * 8;
      bf16x8 vf0 = *reinterpret_cast<const bf16x8*>(vr);
      bf16x8 vf1 = *reinterpret_cast<const bf16x8*>(vr + 32);
      acco[db] = __builtin_amdgcn_mfma_f32_16x16x32_bf16(pf0, vf0, acco[db], 0, 0, 0);
      acco[db] = __builtin_amdgcn_mfma_f32_16x16x32_bf16(pf1, vf1, acco[db], 0, 0, 0);
    }
  }

  const int b = bh >> 4, h = bh & 15;
  #pragma unroll
  for (int db = 0; db < 4; ++db)
    #pragma unroll
    for (int j = 0; j < 4; ++j) {
      int rowg = qrow0 + hl * 4 + j;
      float o = acco[db][j] / lrow[j];
      ao[((size_t)(b * S_LEN) + rowg) * D_MODEL + h * D_HEAD + db * 16 + cl] = f2bf(o);
    }
}

// ---------------------------------------------------------------------------
extern "C" void kernel_launch(void* const* d_in, const int* in_sizes, int n_in,
                              void* d_out, int out_size, void* d_ws, size_t ws_size,
                              hipStream_t stream) {
  const float* x      = (const float*)d_in[0];
  const float* attn_w = (const float*)d_in[1];
  const float* attn_b = (const float*)d_in[2];
  const float* proj_w = (const float*)d_in[3];
  const float* proj_b = (const float*)d_in[4];
  float* out = (float*)d_out;
  char* ws = (char*)d_ws;

  bf16_t* xb  = (bf16_t*)(ws + OFF_XB);
  bf16_t* wb  = (bf16_t*)(ws + OFF_WB);
  bf16_t* pwb = (bf16_t*)(ws + OFF_PWB);
  bf16_t* qb  = (bf16_t*)(ws + OFF_Q);
  bf16_t* kb  = (bf16_t*)(ws + OFF_K);
  bf16_t* vtb = (bf16_t*)(ws + OFF_VT);
  bf16_t* aob = (bf16_t*)(ws + OFF_AO);

  {
    int n4 = M_ROWS * D_MODEL / 4;
    cvt_f32_bf16<<<n4 / 256, 256, 0, stream>>>(x, xb, n4);
  }
  {
    int n4 = QKV_N * D_MODEL / 4;
    cvt_f32_bf16<<<n4 / 256, 256, 0, stream>>>(attn_w, wb, n4);
  }
  {
    int n4 = D_MODEL * D_MODEL / 4;
    cvt_f32_bf16<<<n4 / 256, 256, 0, stream>>>(proj_w, pwb, n4);
  }

  gemm_bt<0><<<dim3(QKV_N / BN, M_ROWS / BM), 256, 0, stream>>>(
      xb, wb, attn_b, nullptr, qb, kb, vtb, M_ROWS, QKV_N, D_MODEL);

  attn_fwd<<<dim3(S_LEN / 64, B_SZ * N_HEADS), 256, 0, stream>>>(qb, kb, vtb, aob);

  gemm_bt<1><<<dim3(D_MODEL / BN, M_ROWS / BM), 256, 0, stream>>>(
      aob, pwb, proj_b, out, nullptr, nullptr, nullptr, M_ROWS, D_MODEL, D_MODEL);
}

// Round 2
// 182.330 us; speedup vs baseline: 1.6711x; 1.6711x over previous
//
#include <hip/hip_runtime.h>
#include <hip/hip_bf16.h>
#include <stdint.h>

// ---------------------------------------------------------------------------
// OptimizedMultiHeadAttn: x:[2,2048,1024] f32, attn_w:[3072,1024], attn_b:[3072],
// proj_w:[1024,1024], proj_b:[1024]  ->  out:[2,2048,1024] f32
// Pipeline: cvt(x,attn_w,proj_w -> bf16) -> QKV gemm_bt (scatter to Q/K/V^T)
//           -> flash attention (causal) -> proj gemm_bt (f32 out + bias)
// ---------------------------------------------------------------------------

typedef __bf16 bf16_t;
typedef __bf16 bf16x8 __attribute__((ext_vector_type(8)));
typedef float f32x4 __attribute__((ext_vector_type(4)));

#define B_SZ 2
#define S_LEN 2048
#define D_MODEL 1024
#define N_HEADS 16
#define D_HEAD 64
#define M_ROWS (B_SZ * S_LEN)          // 4096
#define QKV_N (3 * N_HEADS * D_HEAD)   // 3072

// workspace layout (bytes); total 48 MiB
#define OFF_XB  (0ull)          // x bf16      [4096,1024]  8 MiB
#define OFF_WB  (8ull  << 20)   // attn_w bf16 [3072,1024]  6 MiB
#define OFF_PWB (14ull << 20)   // proj_w bf16 [1024,1024]  2 MiB
#define OFF_Q   (16ull << 20)   // Q bf16 [B,H,S,DK], pre-scaled by 0.125
#define OFF_K   (24ull << 20)   // K bf16 [B,H,S,DK]
#define OFF_VT  (32ull << 20)   // V^T bf16 [B,H,DK,S]
#define OFF_AO  (40ull << 20)   // attn out bf16 [4096,1024]

__device__ __forceinline__ unsigned short f2bf_u(float f) {
  union { float f; unsigned u; } v; v.f = f;
  unsigned r = v.u + 0x7fffu + ((v.u >> 16) & 1u);  // RNE
  return (unsigned short)(r >> 16);
}
__device__ __forceinline__ bf16_t f2bf(float f) {
  unsigned short u = f2bf_u(f);
  return __builtin_bit_cast(bf16_t, u);
}

// ---------------------------------------------------------------------------
__global__ void cvt_f32_bf16(const float* __restrict__ src,
                             bf16_t* __restrict__ dst, int n4) {
  int i = blockIdx.x * blockDim.x + threadIdx.x;
  if (i >= n4) return;
  float4 f = reinterpret_cast<const float4*>(src)[i];
  ushort4 o;
  o.x = f2bf_u(f.x); o.y = f2bf_u(f.y); o.z = f2bf_u(f.z); o.w = f2bf_u(f.w);
  reinterpret_cast<ushort4*>(dst)[i] = o;
}

// ---------------------------------------------------------------------------
// gemm_bt: C[M,N] = A[M,K] * Bt[N,K]^T + bias, 128x128 tile, BK=64, 4 waves.
#define BM 128
#define BN 128
#define BK 64

__device__ __forceinline__ void gload_lds16(const bf16_t* g, bf16_t* l) {
  __builtin_amdgcn_global_load_lds((__attribute__((address_space(1))) void*)g,
                                   (__attribute__((address_space(3))) void*)l,
                                   16, 0, 0);
}

__device__ __forceinline__ bf16x8 lds_frag(const bf16_t* lds, int row, int kchunk) {
  int pos = kchunk ^ (row & 7);
  return *reinterpret_cast<const bf16x8*>(lds + row * BK + pos * 8);
}

// EPI 0: QKV epilogue (scatter bf16 Q/K/V^T, Q pre-scaled 0.125)
// EPI 1: proj epilogue (f32 out + bias)
template <int EPI>
__global__ __launch_bounds__(256, 2) void gemm_bt(
    const bf16_t* __restrict__ A, const bf16_t* __restrict__ Bt,
    const float* __restrict__ bias,
    float* __restrict__ fout,
    bf16_t* __restrict__ qout, bf16_t* __restrict__ kout,
    bf16_t* __restrict__ vtout,
    int M, int N, int K) {
  __shared__ bf16_t As[BM * BK];
  __shared__ bf16_t Bs[BN * BK];
  const int tid = threadIdx.x;
  const int lane = tid & 63;
  const int wid = tid >> 6;
  const int wr = wid >> 1, wc = wid & 1;
  const int cl = lane & 15, hl = lane >> 4;
  const int m0 = blockIdx.y * BM, n0 = blockIdx.x * BN;

  f32x4 acc[4][4];
  #pragma unroll
  for (int m = 0; m < 4; ++m)
    #pragma unroll
    for (int n = 0; n < 4; ++n)
      acc[m][n] = (f32x4){0.f, 0.f, 0.f, 0.f};

  for (int kt = 0; kt < K; kt += BK) {
    #pragma unroll
    for (int it = 0; it < 4; ++it) {
      int chunk = it * 256 + tid;
      int row = chunk >> 3, cpos = chunk & 7;
      int csrc = cpos ^ (row & 7);                     // inverse-swizzled source
      bf16_t* ldsA = As + (it * 256 + wid * 64) * 8;   // wave-uniform dest base
      bf16_t* ldsB = Bs + (it * 256 + wid * 64) * 8;
      gload_lds16(A  + (size_t)(m0 + row) * K + kt + csrc * 8, ldsA);
      gload_lds16(Bt + (size_t)(n0 + row) * K + kt + csrc * 8, ldsB);
    }
    __syncthreads();

    bf16x8 af[2][4], bfr[2][4];
    #pragma unroll
    for (int kk = 0; kk < 2; ++kk) {
      #pragma unroll
      for (int m = 0; m < 4; ++m)
        af[kk][m] = lds_frag(As, wr * 64 + m * 16 + cl, kk * 4 + hl);
      #pragma unroll
      for (int n = 0; n < 4; ++n)
        bfr[kk][n] = lds_frag(Bs, wc * 64 + n * 16 + cl, kk * 4 + hl);
    }
    #pragma unroll
    for (int m = 0; m < 4; ++m)
      #pragma unroll
      for (int n = 0; n < 4; ++n) {
        acc[m][n] = __builtin_amdgcn_mfma_f32_16x16x32_bf16(af[0][m], bfr[0][n], acc[m][n], 0, 0, 0);
        acc[m][n] = __builtin_amdgcn_mfma_f32_16x16x32_bf16(af[1][m], bfr[1][n], acc[m][n], 0, 0, 0);
      }
    __syncthreads();
  }

  // epilogue: C/D layout col=lane&15, row=(lane>>4)*4+j (m89-verified)
  #pragma unroll
  for (int n = 0; n < 4; ++n) {
    int ng = n0 + wc * 64 + n * 16 + cl;
    float bv = bias[ng];
    if constexpr (EPI == 0) {
      int part = ng >> 10;         // 0=Q 1=K 2=V
      int r = ng & 1023;
      int h = r >> 6, dk = r & 63;
      #pragma unroll
      for (int m = 0; m < 4; ++m)
        #pragma unroll
        for (int j = 0; j < 4; ++j) {
          int mg = m0 + wr * 64 + m * 16 + hl * 4 + j;
          int b = mg >> 11, s = mg & 2047;
          float val = acc[m][n][j] + bv;
          size_t bh = (size_t)(b * N_HEADS + h);
          if (part == 0)
            qout[(bh * S_LEN + s) * D_HEAD + dk] = f2bf(val * 0.125f);
          else if (part == 1)
            kout[(bh * S_LEN + s) * D_HEAD + dk] = f2bf(val);
          else
            vtout[(bh * D_HEAD + dk) * S_LEN + s] = f2bf(val);
        }
    } else {
      #pragma unroll
      for (int m = 0; m < 4; ++m)
        #pragma unroll
        for (int j = 0; j < 4; ++j) {
          int mg = m0 + wr * 64 + m * 16 + hl * 4 + j;
          fout[(size_t)mg * N + ng] = acc[m][n][j] + bv;
        }
    }
  }
}

// ---------------------------------------------------------------------------
// Flash attention, causal. Grid (B*H, S/128). Block = 4 waves = 128 q-rows;
// each wave owns rows {base+w*16, base+64+w*16} (two 16-row fragments,
// stride-64 so per-wave causal work is balanced). KBLK=64. Long-first
// dispatch (qt descending) for tail packing. Fully-masked fragments skipped.
__global__ __launch_bounds__(256, 2) void attn_fwd(
    const bf16_t* __restrict__ q,    // [B,H,S,DK], pre-scaled by 0.125
    const bf16_t* __restrict__ k,    // [B,H,S,DK]
    const bf16_t* __restrict__ vt,   // [B,H,DK,S]
    bf16_t* __restrict__ ao) {       // [B*S, H*DK]
  const int bh = blockIdx.x;
  const int qt = (S_LEN / 128 - 1) - blockIdx.y;   // long blocks first
  const int tid = threadIdx.x;
  const int lane = tid & 63, w = tid >> 6;
  const int cl = lane & 15, hl = lane >> 4;
  const bf16_t* qb = q + (size_t)bh * S_LEN * D_HEAD;
  const bf16_t* kb = k + (size_t)bh * S_LEN * D_HEAD;
  const bf16_t* vb = vt + (size_t)bh * D_HEAD * S_LEN;
  const int qbase = qt * 128;
  const int row0[2] = { qbase + w * 16, qbase + 64 + w * 16 };

  __shared__ bf16_t plds[4][32][72];   // per-wave P tiles, padded stride

  // Q fragments (A-operand): row=lane&15, k=(lane>>4)*8 (+32 for second half)
  bf16x8 qf[2][2];
  #pragma unroll
  for (int rf = 0; rf < 2; ++rf) {
    const bf16_t* qr = qb + (size_t)(row0[rf] + cl) * D_HEAD + hl * 8;
    qf[rf][0] = *reinterpret_cast<const bf16x8*>(qr);
    qf[rf][1] = *reinterpret_cast<const bf16x8*>(qr + 32);
  }

  float mrow[2][4], lrow[2][4];
  f32x4 acco[2][4];
  #pragma unroll
  for (int rf = 0; rf < 2; ++rf) {
    #pragma unroll
    for (int j = 0; j < 4; ++j) { mrow[rf][j] = -1e30f; lrow[rf][j] = 0.f; }
    #pragma unroll
    for (int db = 0; db < 4; ++db) acco[rf][db] = (f32x4){0.f, 0.f, 0.f, 0.f};
  }

  const int ktend = 2 * qt + 1;
  for (int kt = 0; kt <= ktend; ++kt) {
    // K fragments, shared by both row-fragments
    bf16x8 kf[4][2];
    #pragma unroll
    for (int nb = 0; nb < 4; ++nb) {
      const bf16_t* kr = kb + (size_t)(kt * 64 + nb * 16 + cl) * D_HEAD + hl * 8;
      kf[nb][0] = *reinterpret_cast<const bf16x8*>(kr);
      kf[nb][1] = *reinterpret_cast<const bf16x8*>(kr + 32);
    }

    const bool act0 = (kt * 64) <= (row0[0] + 15);
    const bool act1 = (kt * 64) <= (row0[1] + 15);

    // QK^T for both fragments
    f32x4 sacc[2][4];
    #pragma unroll
    for (int rf = 0; rf < 2; ++rf) {
      const bool act = rf ? act1 : act0;
      if (!act) continue;
      #pragma unroll
      for (int nb = 0; nb < 4; ++nb) {
        f32x4 s = (f32x4){0.f, 0.f, 0.f, 0.f};
        s = __builtin_amdgcn_mfma_f32_16x16x32_bf16(qf[rf][0], kf[nb][0], s, 0, 0, 0);
        s = __builtin_amdgcn_mfma_f32_16x16x32_bf16(qf[rf][1], kf[nb][1], s, 0, 0, 0);
        sacc[rf][nb] = s;
      }
    }

    // V fragments issued early (in flight under softmax)
    bf16x8 vf[4][2];
    #pragma unroll
    for (int db = 0; db < 4; ++db) {
      const bf16_t* vr = vb + (size_t)(db * 16 + cl) * S_LEN + kt * 64 + hl * 8;
      vf[db][0] = *reinterpret_cast<const bf16x8*>(vr);
      vf[db][1] = *reinterpret_cast<const bf16x8*>(vr + 32);
    }

    // softmax + P->LDS
    #pragma unroll
    for (int rf = 0; rf < 2; ++rf) {
      const bool act = rf ? act1 : act0;
      if (!act) continue;
      if (kt * 64 + 63 > row0[rf]) {  // diagonal overlap: causal mask
        #pragma unroll
        for (int nb = 0; nb < 4; ++nb)
          #pragma unroll
          for (int j = 0; j < 4; ++j) {
            int colg = kt * 64 + nb * 16 + cl;
            int rowg = row0[rf] + hl * 4 + j;
            if (colg > rowg) sacc[rf][nb][j] = -1e30f;
          }
      }
      #pragma unroll
      for (int j = 0; j < 4; ++j) {
        float tmax = fmaxf(fmaxf(sacc[rf][0][j], sacc[rf][1][j]),
                           fmaxf(sacc[rf][2][j], sacc[rf][3][j]));
        tmax = fmaxf(tmax, __shfl_xor(tmax, 1));
        tmax = fmaxf(tmax, __shfl_xor(tmax, 2));
        tmax = fmaxf(tmax, __shfl_xor(tmax, 4));
        tmax = fmaxf(tmax, __shfl_xor(tmax, 8));
        float mnew = fmaxf(mrow[rf][j], tmax);
        float corr = __expf(mrow[rf][j] - mnew);
        mrow[rf][j] = mnew;
        float rsum = 0.f;
        #pragma unroll
        for (int nb = 0; nb < 4; ++nb) {
          float p = __expf(sacc[rf][nb][j] - mnew);
          sacc[rf][nb][j] = p;
          rsum += p;
        }
        rsum += __shfl_xor(rsum, 1);
        rsum += __shfl_xor(rsum, 2);
        rsum += __shfl_xor(rsum, 4);
        rsum += __shfl_xor(rsum, 8);
        lrow[rf][j] = lrow[rf][j] * corr + rsum;
        #pragma unroll
        for (int db = 0; db < 4; ++db) acco[rf][db][j] *= corr;
      }
      #pragma unroll
      for (int nb = 0; nb < 4; ++nb)
        #pragma unroll
        for (int j = 0; j < 4; ++j)
          plds[w][rf * 16 + hl * 4 + j][nb * 16 + cl] = f2bf(sacc[rf][nb][j]);
    }

    // PV
    #pragma unroll
    for (int rf = 0; rf < 2; ++rf) {
      const bool act = rf ? act1 : act0;
      if (!act) continue;
      bf16x8 pf0 = *reinterpret_cast<const bf16x8*>(&plds[w][rf * 16 + cl][hl * 8]);
      bf16x8 pf1 = *reinterpret_cast<const bf16x8*>(&plds[w][rf * 16 + cl][32 + hl * 8]);
      #pragma unroll
      for (int db = 0; db < 4; ++db) {
        acco[rf][db] = __builtin_amdgcn_mfma_f32_16x16x32_bf16(pf0, vf[db][0], acco[rf][db], 0, 0, 0);
        acco[rf][db] = __builtin_amdgcn_mfma_f32_16x16x32_bf16(pf1, vf[db][1], acco[rf][db], 0, 0, 0);
      }
    }
  }

  const int b = bh >> 4, h = bh & 15;
  #pragma unroll
  for (int rf = 0; rf < 2; ++rf)
    #pragma unroll
    for (int db = 0; db < 4; ++db)
      #pragma unroll
      for (int j = 0; j < 4; ++j) {
        int rowg = row0[rf] + hl * 4 + j;
        float o = acco[rf][db][j] / lrow[rf][j];
        ao[((size_t)(b * S_LEN) + rowg) * D_MODEL + h * D_HEAD + db * 16 + cl] = f2bf(o);
      }
}

// ---------------------------------------------------------------------------
extern "C" void kernel_launch(void* const* d_in, const int* in_sizes, int n_in,
                              void* d_out, int out_size, void* d_ws, size_t ws_size,
                              hipStream_t stream) {
  const float* x      = (const float*)d_in[0];
  const float* attn_w = (const float*)d_in[1];
  const float* attn_b = (const float*)d_in[2];
  const float* proj_w = (const float*)d_in[3];
  const float* proj_b = (const float*)d_in[4];
  float* out = (float*)d_out;
  char* ws = (char*)d_ws;

  bf16_t* xb  = (bf16_t*)(ws + OFF_XB);
  bf16_t* wb  = (bf16_t*)(ws + OFF_WB);
  bf16_t* pwb = (bf16_t*)(ws + OFF_PWB);
  bf16_t* qb  = (bf16_t*)(ws + OFF_Q);
  bf16_t* kb  = (bf16_t*)(ws + OFF_K);
  bf16_t* vtb = (bf16_t*)(ws + OFF_VT);
  bf16_t* aob = (bf16_t*)(ws + OFF_AO);

  {
    int n4 = M_ROWS * D_MODEL / 4;
    cvt_f32_bf16<<<n4 / 256, 256, 0, stream>>>(x, xb, n4);
  }
  {
    int n4 = QKV_N * D_MODEL / 4;
    cvt_f32_bf16<<<n4 / 256, 256, 0, stream>>>(attn_w, wb, n4);
  }
  {
    int n4 = D_MODEL * D_MODEL / 4;
    cvt_f32_bf16<<<n4 / 256, 256, 0, stream>>>(proj_w, pwb, n4);
  }

  gemm_bt<0><<<dim3(QKV_N / BN, M_ROWS / BM), 256, 0, stream>>>(
      xb, wb, attn_b, nullptr, qb, kb, vtb, M_ROWS, QKV_N, D_MODEL);

  attn_fwd<<<dim3(B_SZ * N_HEADS, S_LEN / 128), 256, 0, stream>>>(qb, kb, vtb, aob);

  gemm_bt<1><<<dim3(D_MODEL / BN, M_ROWS / BM), 256, 0, stream>>>(
      aob, pwb, proj_b, out, nullptr, nullptr, nullptr, M_ROWS, D_MODEL, D_MODEL);
}